// Round 8
// baseline (450.703 us; speedup 1.0000x reference)
//
#include <hip/hip_runtime.h>

// PointNet on MI355X. B=32, P=2048, K=16, NHID=128, NCLS=10.
//   K1 knn      : brute-force; LDS Q'=(-2x,-2y,-2z,|q|^2) -> 3 FMA/candidate; per-lane top-3 via
//                 min/med3; ballot binary search for 16th-smallest; set emission; exact rare fallback.
//                 SPLIT INTO 2 DISPATCHES (graphs 0-15 / 16-31) so layer kernels surface in rocprof top-5.
//   K2 layer1   : msg = relu(pos_j*(A+B) + (b1a - pos_p*B)); v = msg @ W1b (MFMA); h1 = relu(max_k v + b1b)
//                 LDS row stride 132 (was 136: 68-dword stride -> 8-way bank conflicts on ds_read_b128).
//   K3 midgemm  : u2' = [h1|pos|0] @ W2a(all 131 rows) + b2a -> bf16. Wt stride 164 (was 168).
//   K4 layer2   : msg = relu(u2'[j] - pos_p*R); v = msg @ W2b (MFMA); fused global max pool. stride 132.
//   K5 cls      : out = g @ Wc + bc
// MFMA layouts per verified m89/m97 mappings.

typedef __bf16 bf16x8 __attribute__((ext_vector_type(8)));
typedef float  f32x4  __attribute__((ext_vector_type(4)));

#define LDSA __attribute__((aligned(16)))
#define WAVE_LDS_SYNC() __asm__ volatile("s_waitcnt lgkmcnt(0)" ::: "memory")

// ---------------------------------------------------------------- K1: KNN
__global__ __launch_bounds__(512) void knn_kernel(const float* __restrict__ pos,
                                                  int* __restrict__ nbr, int blk0) {
  __shared__ LDSA float4 P4[2048];  // {-2x, -2y, -2z, |q|^2}
  const int blk = blockIdx.x + blk0;
  const int b = blk >> 5;
  const int tid = threadIdx.x;
  const size_t bbase = (size_t)b * 2048;
  for (int idx = tid; idx < 2048; idx += 512) {
    const float* pp = pos + (bbase + idx) * 3;
    float x = pp[0], y = pp[1], z = pp[2];
    P4[idx] = make_float4(-2.0f * x, -2.0f * y, -2.0f * z, fmaf(z, z, fmaf(y, y, x * x)));
  }
  __syncthreads();
  const int wave = tid >> 6, lane = tid & 63;
  const int p0 = (blk & 31) * 64 + wave * 8;   // 8 points per wave
  const unsigned long long below = (1ull << lane) - 1ull;
  const float FINF = __uint_as_float(0x7F800000u);
  for (int it = 0; it < 8; ++it) {
    const int pl = p0 + it;
    const float4 Qp = P4[pl];
    const float Px = -0.5f * Qp.x, Py = -0.5f * Qp.y, Pz = -0.5f * Qp.z;
    // ---- phase 1: streaming per-lane sorted top-3 (3 FMA + min/med3 + idx selects) ----
    float m1 = FINF, m2 = FINF, m3 = FINF;
    unsigned s1 = 0, s2 = 0, s3 = 0;
#pragma unroll 8
    for (int i = 0; i < 32; ++i) {
      int c = lane + (i << 6);
      float4 Q = P4[c];
      float d2 = fmaf(Px, Q.x, fmaf(Py, Q.y, fmaf(Pz, Q.z, Q.w)));
      bool c1 = d2 < m1, c2 = d2 < m2, c3 = d2 < m3;
      float n3 = __builtin_amdgcn_fmed3f(d2, m2, m3);
      float n2 = __builtin_amdgcn_fmed3f(d2, m1, m2);
      float n1 = fminf(d2, m1);
      s3 = c2 ? s2 : (c3 ? (unsigned)c : s3);
      s2 = c1 ? s1 : (c2 ? (unsigned)c : s2);
      s1 = c1 ? (unsigned)c : s1;
      m1 = n1; m2 = n2; m3 = n3;
    }
    // ---- monotone float->u32 keys ----
    unsigned u;
    unsigned k1, k2, k3;
    u = __float_as_uint(m1); k1 = ((int)u < 0) ? ~u : (u | 0x80000000u);
    u = __float_as_uint(m2); k2 = ((int)u < 0) ? ~u : (u | 0x80000000u);
    u = __float_as_uint(m3); k3 = ((int)u < 0) ? ~u : (u | 0x80000000u);
    // ---- phase 2: ballot binary search for V = 16th-smallest buffered key ----
    unsigned v = 0;
#pragma unroll
    for (int bit = 31; bit >= 0; --bit) {
      unsigned t = v | (1u << bit);
      int cnt = __popcll(__ballot(k1 < t)) + __popcll(__ballot(k2 < t)) +
                __popcll(__ballot(k3 < t));
      if (cnt < 16) v = t;
    }
    const unsigned V = v;
    const long long outbase = ((long long)bbase + pl) * 16;
    if (__any(k3 < V)) {
      // ---- exact fallback (~1% of points) ----
      unsigned long long K1 = ((unsigned long long)k1 << 32) | s1;
      unsigned long long K2 = ((unsigned long long)k2 << 32) | s2;
      unsigned long long K3 = ((unsigned long long)k3 << 32) | s3;
      unsigned long long lastk = 0;
      for (int r = 0; r < 16; ++r) {
        unsigned long long k = K1, kmin = K1;
#pragma unroll
        for (int off = 1; off < 64; off <<= 1) {
          unsigned long long o = __shfl_xor(kmin, off);
          kmin = (o < kmin) ? o : kmin;
        }
        if (lane == r) nbr[outbase + r] = (int)(kmin & 0xFFFFFFFFull);
        if (k == kmin) { lastk = k; K1 = K2; K2 = K3; K3 = ~0ull; }
        if (r < 15 && __any(K1 == ~0ull)) {
          if (K1 == ~0ull) {
            unsigned long long best = ~0ull;
            for (int i = 0; i < 32; ++i) {
              int c = lane + (i << 6);
              float4 Q = P4[c];
              float d2 = fmaf(Px, Q.x, fmaf(Py, Q.y, fmaf(Pz, Q.z, Q.w)));
              unsigned uu = __float_as_uint(d2);
              uu = ((int)uu < 0) ? ~uu : (uu | 0x80000000u);
              unsigned long long kc = ((unsigned long long)uu << 32) | (unsigned)c;
              bool ok = (kc > lastk) & (kc < best);
              best = ok ? kc : best;
            }
            K1 = best;
          }
        }
      }
    } else {
      // ---- set emission ----
      unsigned long long L1 = __ballot(k1 < V), L2 = __ballot(k2 < V), L3 = __ballot(k3 < V);
      unsigned long long E1 = __ballot(k1 == V), E2 = __ballot(k2 == V), E3 = __ballot(k3 == V);
      int cA = __popcll(L1), cB = cA + __popcll(L2), cT = cB + __popcll(L3);
      int eA = __popcll(E1), eB = eA + __popcll(E2);
      {
        bool lt = k1 < V, eq = k1 == V;
        int plt = __popcll(L1 & below);
        int peq = cT + __popcll(E1 & below);
        int p = lt ? plt : peq;
        if (lt || (eq && peq < 16)) nbr[outbase + p] = (int)s1;
      }
      {
        bool lt = k2 < V, eq = k2 == V;
        int plt = cA + __popcll(L2 & below);
        int peq = cT + eA + __popcll(E2 & below);
        int p = lt ? plt : peq;
        if (lt || (eq && peq < 16)) nbr[outbase + p] = (int)s2;
      }
      {
        bool lt = k3 < V, eq = k3 == V;
        int plt = cB + __popcll(L3 & below);
        int peq = cT + eB + __popcll(E3 & below);
        int p = lt ? plt : peq;
        if (lt || (eq && peq < 16)) nbr[outbase + p] = (int)s3;
      }
    }
  }
}

// ---------------------------------------------------------------- K2: layer 1
__global__ __launch_bounds__(256, 2) void layer1_kernel(
    const float* __restrict__ pos, const int* __restrict__ nbr,
    const float* __restrict__ W1a, const float* __restrict__ b1a,
    const float* __restrict__ W1b, const float* __restrict__ b1b,
    __bf16* __restrict__ h1e) {
  // Wbt: 128 rows x stride 132 bf16 = 33792 B; aliased after use with { mt 4x4224 B ; base 4x512 B }
  __shared__ LDSA char smem[33792];
  __bf16* Wbt = (__bf16*)smem;
  const int tid = threadIdx.x;
  for (int idx = tid; idx < 16384; idx += 256) {
    int k = idx >> 7, n = idx & 127;
    Wbt[n * 132 + k] = (__bf16)W1b[idx];
  }
  __syncthreads();
  const int wave = tid >> 6, lane = tid & 63;
  const int q = lane >> 4, c15 = lane & 15;
  bf16x8 bfr[8][4];  // W1b^T fragments resident (128 VGPRs)
#pragma unroll
  for (int nt = 0; nt < 8; ++nt)
#pragma unroll
    for (int t = 0; t < 4; ++t)
      bfr[nt][t] = *(const bf16x8*)&Wbt[(nt * 16 + c15) * 132 + t * 32 + q * 8];
  __syncthreads();  // Wbt dead: space reused for mt/base
  __bf16* mt = (__bf16*)smem + wave * 2112;          // [16 rows][132]
  float* base = (float*)(smem + 16896) + wave * 128;
  const int cb = lane & 7, k0 = lane >> 3, C0 = cb * 16;
  float4 s0h[4], s1h[4], s2h[4];  // (A+B) rows for this lane's 16 channels
#pragma unroll
  for (int i = 0; i < 4; ++i) {
    float4 a0 = *(const float4*)&W1a[      C0 + 4 * i], r0 = *(const float4*)&W1a[384 + C0 + 4 * i];
    float4 a1 = *(const float4*)&W1a[128 + C0 + 4 * i], r1 = *(const float4*)&W1a[512 + C0 + 4 * i];
    float4 a2 = *(const float4*)&W1a[256 + C0 + 4 * i], r2 = *(const float4*)&W1a[640 + C0 + 4 * i];
    s0h[i] = make_float4(a0.x + r0.x, a0.y + r0.y, a0.z + r0.z, a0.w + r0.w);
    s1h[i] = make_float4(a1.x + r1.x, a1.y + r1.y, a1.z + r1.z, a1.w + r1.w);
    s2h[i] = make_float4(a2.x + r2.x, a2.y + r2.y, a2.z + r2.z, a2.w + r2.w);
  }
  const int c2 = lane * 2;
  const float br0a = W1a[384 + c2], br0b = W1a[384 + c2 + 1];
  const float br1a = W1a[512 + c2], br1b = W1a[512 + c2 + 1];
  const float br2a = W1a[640 + c2], br2b = W1a[640 + c2 + 1];
  const float ba0 = b1a[c2], ba1 = b1a[c2 + 1];
  const float bbi0 = b1b[q * 32 + c15], bbi1 = b1b[q * 32 + 16 + c15];
  const int blk = blockIdx.x, b = blk >> 5;
  const size_t bbase = (size_t)b * 2048;
  const int p0 = (blk & 31) * 64 + wave * 16;
  size_t node = bbase + p0;
  int j0 = nbr[node * 16 + k0];
  int j1 = nbr[node * 16 + k0 + 8];
  float px = pos[node * 3], py = pos[node * 3 + 1], pz = pos[node * 3 + 2];
  const float* t0 = pos + (bbase + j0) * 3;
  const float* t1 = pos + (bbase + j1) * 3;
  float xa = t0[0], ya = t0[1], za = t0[2];
  float xb = t1[0], yb = t1[1], zb = t1[2];
  for (int it = 0; it < 16; ++it) {
    const float xp = px, yp = py, zp = pz;
    const float xac = xa, yac = ya, zac = za;
    const float xbc = xb, ybc = yb, zbc = zb;
    const size_t nodec = node;
    if (it < 15) {  // prefetch next iteration's full gather chain
      node = nodec + 1;
      j0 = nbr[node * 16 + k0];
      j1 = nbr[node * 16 + k0 + 8];
      px = pos[node * 3]; py = pos[node * 3 + 1]; pz = pos[node * 3 + 2];
      const float* n0 = pos + (bbase + j0) * 3;
      const float* n1 = pos + (bbase + j1) * 3;
      xa = n0[0]; ya = n0[1]; za = n0[2];
      xb = n1[0]; yb = n1[1]; zb = n1[2];
    }
    float v0 = ba0 - fmaf(xp, br0a, fmaf(yp, br1a, zp * br2a));
    float v1 = ba1 - fmaf(xp, br0b, fmaf(yp, br1b, zp * br2b));
    *(float2*)&base[c2] = make_float2(v0, v1);
    WAVE_LDS_SYNC();
    float4 bb[4];
#pragma unroll
    for (int i = 0; i < 4; ++i) bb[i] = *(const float4*)&base[C0 + 4 * i];
#pragma unroll
    for (int r = 0; r < 2; ++r) {
      const float xj = r ? xbc : xac, yj = r ? ybc : yac, zj = r ? zbc : zac;
      bf16x8 o0, o1;
#pragma unroll
      for (int i = 0; i < 4; ++i) {
        float mx = fmaf(xj, s0h[i].x, fmaf(yj, s1h[i].x, fmaf(zj, s2h[i].x, bb[i].x)));
        float my = fmaf(xj, s0h[i].y, fmaf(yj, s1h[i].y, fmaf(zj, s2h[i].y, bb[i].y)));
        float mz = fmaf(xj, s0h[i].z, fmaf(yj, s1h[i].z, fmaf(zj, s2h[i].z, bb[i].z)));
        float mw = fmaf(xj, s0h[i].w, fmaf(yj, s1h[i].w, fmaf(zj, s2h[i].w, bb[i].w)));
        __bf16 e0 = (__bf16)fmaxf(mx, 0.f), e1 = (__bf16)fmaxf(my, 0.f);
        __bf16 e2 = (__bf16)fmaxf(mz, 0.f), e3 = (__bf16)fmaxf(mw, 0.f);
        if (i < 2) { o0[i * 4 + 0] = e0; o0[i * 4 + 1] = e1; o0[i * 4 + 2] = e2; o0[i * 4 + 3] = e3; }
        else { o1[(i - 2) * 4 + 0] = e0; o1[(i - 2) * 4 + 1] = e1; o1[(i - 2) * 4 + 2] = e2; o1[(i - 2) * 4 + 3] = e3; }
      }
      __bf16* dst = &mt[(k0 + 8 * r) * 132 + C0];
      *(bf16x8*)dst = o0;
      *(bf16x8*)(dst + 8) = o1;
    }
    WAVE_LDS_SYNC();
    bf16x8 af[4];
#pragma unroll
    for (int t = 0; t < 4; ++t)
      af[t] = *(const bf16x8*)&mt[c15 * 132 + t * 32 + q * 8];
    f32x4 acc[8] = {};
#pragma unroll
    for (int nt = 0; nt < 8; ++nt)
#pragma unroll
      for (int t = 0; t < 4; ++t)
        acc[nt] = __builtin_amdgcn_mfma_f32_16x16x32_bf16(af[t], bfr[nt][t], acc[nt], 0, 0, 0);
#pragma unroll
    for (int nt = 0; nt < 8; ++nt) {
      float m4 = fmaxf(fmaxf(acc[nt][0], acc[nt][1]), fmaxf(acc[nt][2], acc[nt][3]));
      m4 = fmaxf(m4, __shfl_xor(m4, 16));
      m4 = fmaxf(m4, __shfl_xor(m4, 32));
      if ((nt >> 1) == q) {
        float bias = (nt & 1) ? bbi1 : bbi0;
        h1e[nodec * 160 + nt * 16 + c15] = (__bf16)fmaxf(m4 + bias, 0.f);
      }
    }
    if (lane < 32) {  // append pos (bf16) + zero pad: cols 128..159
      __bf16 v = (__bf16)0.f;
      if (lane == 0) v = (__bf16)xp;
      else if (lane == 1) v = (__bf16)yp;
      else if (lane == 2) v = (__bf16)zp;
      h1e[nodec * 160 + 128 + lane] = v;
    }
  }
}

// ---------------------------------------------------------------- K3: u2' = [h1|pos|0] @ W2a + b2a (bf16 out)
__global__ __launch_bounds__(256) void mid_gemm_kernel(
    const __bf16* __restrict__ h1e, const float* __restrict__ W2a,
    const float* __restrict__ b2a, __bf16* __restrict__ u2p) {
  __shared__ LDSA __bf16 Wt[128 * 164];  // W2a^T [n][k], k padded 131->164
  const int tid = threadIdx.x;
  uint4 z = make_uint4(0, 0, 0, 0);
  for (int idx = tid; idx < 2624; idx += 256) ((uint4*)Wt)[idx] = z;
  __syncthreads();
  for (int idx = tid; idx < 131 * 32; idx += 256) {
    int k = idx >> 5, c4 = (idx & 31) * 4;
    float4 w = *(const float4*)&W2a[k * 128 + c4];
    Wt[(c4 + 0) * 164 + k] = (__bf16)w.x;
    Wt[(c4 + 1) * 164 + k] = (__bf16)w.y;
    Wt[(c4 + 2) * 164 + k] = (__bf16)w.z;
    Wt[(c4 + 3) * 164 + k] = (__bf16)w.w;
  }
  const int wave = tid >> 6, lane = tid & 63;
  const int q = lane >> 4, c15 = lane & 15;
  float biasr[8];
#pragma unroll
  for (int nt = 0; nt < 8; ++nt) biasr[nt] = b2a[nt * 16 + c15];
  __syncthreads();
  for (int tile = 0; tile < 4; ++tile) {  // 4 row-tiles/block: staging amortized
    const int row0 = blockIdx.x * 256 + tile * 64 + wave * 16;
    bf16x8 af[5];
#pragma unroll
    for (int t = 0; t < 5; ++t)
      af[t] = *(const bf16x8*)(h1e + (size_t)(row0 + c15) * 160 + t * 32 + q * 8);
    f32x4 acc[8] = {};
#pragma unroll
    for (int nt = 0; nt < 8; ++nt)
#pragma unroll
      for (int t = 0; t < 5; ++t) {
        bf16x8 bf = *(const bf16x8*)&Wt[(nt * 16 + c15) * 164 + t * 32 + q * 8];
        acc[nt] = __builtin_amdgcn_mfma_f32_16x16x32_bf16(af[t], bf, acc[nt], 0, 0, 0);
      }
#pragma unroll
    for (int nt = 0; nt < 8; ++nt) {
#pragma unroll
      for (int r = 0; r < 4; ++r)
        u2p[(size_t)(row0 + q * 4 + r) * 128 + nt * 16 + c15] = (__bf16)(acc[nt][r] + biasr[nt]);
    }
  }
}

// ---------------------------------------------------------------- K4: layer 2 + fused max pool
__global__ __launch_bounds__(256, 2) void layer2_kernel(
    const float* __restrict__ pos, const int* __restrict__ nbr,
    const __bf16* __restrict__ u2p, const float* __restrict__ W2a,
    const float* __restrict__ W2b, const float* __restrict__ b2b,
    int* __restrict__ gG) {
  __shared__ LDSA char smem[33792];  // Wbt (stride 132) aliased with { mt ; proj }
  __shared__ int gpart[128];
  __bf16* Wbt = (__bf16*)smem;
  const int tid = threadIdx.x;
  for (int idx = tid; idx < 16384; idx += 256) {
    int k = idx >> 7, n = idx & 127;
    Wbt[n * 132 + k] = (__bf16)W2b[idx];
  }
  if (tid < 128) gpart[tid] = 0;
  __syncthreads();
  const int wave = tid >> 6, lane = tid & 63;
  const int q = lane >> 4, c15 = lane & 15;
  bf16x8 bfr[8][4];
#pragma unroll
  for (int nt = 0; nt < 8; ++nt)
#pragma unroll
    for (int t = 0; t < 4; ++t)
      bfr[nt][t] = *(const bf16x8*)&Wbt[(nt * 16 + c15) * 132 + t * 32 + q * 8];
  __syncthreads();  // Wbt dead
  __bf16* mt = (__bf16*)smem + wave * 2112;
  float* proj = (float*)(smem + 16896) + wave * 128;
  const int cb = lane & 7, k0 = lane >> 3, C0 = cb * 16;
  const int c2 = lane * 2;
  const float r0a = W2a[16384 + c2], r0b = W2a[16384 + c2 + 1];
  const float r1a = W2a[16512 + c2], r1b = W2a[16512 + c2 + 1];
  const float r2a = W2a[16640 + c2], r2b = W2a[16640 + c2 + 1];
  const float bbi0 = b2b[q * 32 + c15], bbi1 = b2b[q * 32 + 16 + c15];
  // XCD swizzle: graph g's 32 blocks -> one XCD (perf-only)
  const int lb = blockIdx.x;
  const int xcd = lb & 7, slot = lb >> 3;
  const int b = xcd + 8 * (slot >> 5);
  const int bi = slot & 31;
  const size_t bbase = (size_t)b * 2048;
  const int p0 = bi * 64 + wave * 16;
  size_t node = bbase + p0;
  int j0 = nbr[node * 16 + k0];
  int j1 = nbr[node * 16 + k0 + 8];
  float px = pos[node * 3], py = pos[node * 3 + 1], pz = pos[node * 3 + 2];
  const __bf16* g0 = u2p + (size_t)(bbase + j0) * 128 + C0;
  const __bf16* g1 = u2p + (size_t)(bbase + j1) * 128 + C0;
  bf16x8 ua0 = *(const bf16x8*)g0, ua1 = *(const bf16x8*)(g0 + 8);
  bf16x8 ub0 = *(const bf16x8*)g1, ub1 = *(const bf16x8*)(g1 + 8);
  for (int it = 0; it < 16; ++it) {
    const float xp = px, yp = py, zp = pz;
    const bf16x8 ua0c = ua0, ua1c = ua1, ub0c = ub0, ub1c = ub1;
    const size_t nodec = node;
    if (it < 15) {
      node = nodec + 1;
      j0 = nbr[node * 16 + k0];
      j1 = nbr[node * 16 + k0 + 8];
      px = pos[node * 3]; py = pos[node * 3 + 1]; pz = pos[node * 3 + 2];
      const __bf16* n0 = u2p + (size_t)(bbase + j0) * 128 + C0;
      const __bf16* n1 = u2p + (size_t)(bbase + j1) * 128 + C0;
      ua0 = *(const bf16x8*)n0; ua1 = *(const bf16x8*)(n0 + 8);
      ub0 = *(const bf16x8*)n1; ub1 = *(const bf16x8*)(n1 + 8);
    }
    float v0 = fmaf(xp, r0a, fmaf(yp, r1a, zp * r2a));
    float v1 = fmaf(xp, r0b, fmaf(yp, r1b, zp * r2b));
    *(float2*)&proj[c2] = make_float2(v0, v1);
    WAVE_LDS_SYNC();
    float pj[16];
#pragma unroll
    for (int i = 0; i < 4; ++i) *(float4*)&pj[4 * i] = *(const float4*)&proj[C0 + 4 * i];
#pragma unroll
    for (int r = 0; r < 2; ++r) {
      bf16x8 u0 = r ? ub0c : ua0c, u1 = r ? ub1c : ua1c;
      bf16x8 o0, o1;
#pragma unroll
      for (int e = 0; e < 8; ++e) o0[e] = (__bf16)fmaxf((float)u0[e] - pj[e], 0.f);
#pragma unroll
      for (int e = 0; e < 8; ++e) o1[e] = (__bf16)fmaxf((float)u1[e] - pj[8 + e], 0.f);
      __bf16* dst = &mt[(k0 + 8 * r) * 132 + C0];
      *(bf16x8*)dst = o0;
      *(bf16x8*)(dst + 8) = o1;
    }
    WAVE_LDS_SYNC();
    bf16x8 af[4];
#pragma unroll
    for (int t = 0; t < 4; ++t)
      af[t] = *(const bf16x8*)&mt[c15 * 132 + t * 32 + q * 8];
    f32x4 acc[8] = {};
#pragma unroll
    for (int nt = 0; nt < 8; ++nt)
#pragma unroll
      for (int t = 0; t < 4; ++t)
        acc[nt] = __builtin_amdgcn_mfma_f32_16x16x32_bf16(af[t], bfr[nt][t], acc[nt], 0, 0, 0);
#pragma unroll
    for (int nt = 0; nt < 8; ++nt) {
      float m4 = fmaxf(fmaxf(acc[nt][0], acc[nt][1]), fmaxf(acc[nt][2], acc[nt][3]));
      m4 = fmaxf(m4, __shfl_xor(m4, 16));
      m4 = fmaxf(m4, __shfl_xor(m4, 32));
      if ((nt >> 1) == q) {
        float bias = (nt & 1) ? bbi1 : bbi0;
        float h = fmaxf(m4 + bias, 0.f);
        atomicMax(&gpart[nt * 16 + c15], __float_as_int(h));  // h>=0: int-max == float-max
      }
    }
  }
  __syncthreads();
  if (tid < 128) atomicMax(&gG[b * 128 + tid], gpart[tid]);
}

// ---------------------------------------------------------------- K5: classifier
__global__ __launch_bounds__(64) void cls_kernel(const int* __restrict__ gG,
                                                 const float* __restrict__ Wc,
                                                 const float* __restrict__ bc,
                                                 float* __restrict__ out) {
  const int b = blockIdx.x, lane = threadIdx.x;
  float g1 = __int_as_float(gG[b * 128 + lane]);
  float g2 = __int_as_float(gG[b * 128 + 64 + lane]);
  float accn[10];
#pragma unroll
  for (int n = 0; n < 10; ++n)
    accn[n] = g1 * Wc[lane * 10 + n] + g2 * Wc[(64 + lane) * 10 + n];
#pragma unroll
  for (int n = 0; n < 10; ++n) {
#pragma unroll
    for (int off = 32; off >= 1; off >>= 1) accn[n] += __shfl_xor(accn[n], off);
  }
  if (lane == 0) {
#pragma unroll
    for (int n = 0; n < 10; ++n) out[b * 10 + n] = accn[n] + bc[n];
  }
}

// ---------------------------------------------------------------- launcher
extern "C" void kernel_launch(void* const* d_in, const int* in_sizes, int n_in,
                              void* d_out, int out_size, void* d_ws, size_t ws_size,
                              hipStream_t stream) {
  const float* pos = (const float*)d_in[0];
  // d_in[1] = batch (unused: graphs are equal-size, sorted)
  const float* W1a = (const float*)d_in[2];
  const float* b1a = (const float*)d_in[3];
  const float* W1b = (const float*)d_in[4];
  const float* b1b = (const float*)d_in[5];
  const float* W2a = (const float*)d_in[6];
  const float* b2a = (const float*)d_in[7];
  const float* W2b = (const float*)d_in[8];
  const float* b2b = (const float*)d_in[9];
  const float* Wc  = (const float*)d_in[10];
  const float* bc  = (const float*)d_in[11];

  char* ws = (char*)d_ws;
  int*    nbr = (int*)ws;                          //  4 MB : [65536][16]
  __bf16* h1e = (__bf16*)(ws + 4194304);           // 20 MB : [65536][160]
  __bf16* u2p = (__bf16*)(ws + 25165824);          // 16 MB : [65536][128] bf16
  int*    gG  = (int*)(ws + 41943040);             // 16 KB : [32][128]
  float*  out = (float*)d_out;

  hipMemsetAsync(gG, 0, 32 * 128 * sizeof(int), stream);  // relu>=0, bits(0)==0.0f
  knn_kernel<<<512, 512, 0, stream>>>(pos, nbr, 0);    // graphs 0-15
  knn_kernel<<<512, 512, 0, stream>>>(pos, nbr, 512);  // graphs 16-31 (split: rocprof visibility)
  layer1_kernel<<<1024, 256, 0, stream>>>(pos, nbr, W1a, b1a, W1b, b1b, h1e);
  mid_gemm_kernel<<<256, 256, 0, stream>>>(h1e, W2a, b2a, u2p);
  layer2_kernel<<<1024, 256, 0, stream>>>(pos, nbr, u2p, W2a, W2b, b2b, gG);
  cls_kernel<<<32, 64, 0, stream>>>(gG, Wc, bc, out);
}

// Round 9
// 352.922 us; speedup vs baseline: 1.2771x; 1.2771x over previous
//
#include <hip/hip_runtime.h>

// PointNet on MI355X. B=32, P=2048, K=16, NHID=128, NCLS=10.
//   K1 knn    : R7 form (124 us known-good): 3-FMA candidates, per-lane top-3 (min/med3),
//               ballot binary search + set emission, exact rare fallback. Single dispatch.
//   K2 layer1 : BLOCK-COOPERATIVE rewrite (R8 evidence: occ 21%, all pipes idle, 128+ VGPR bfr):
//               4 waves split the 8 output tiles (bfr 2x4 = 32 VGPR); per point the block builds
//               one shared 16x136 msg tile (thread = 1 neighbor x 8 channels), double-buffered
//               mt[2]/base[2] -> ONE __syncthreads per point; 64 points/block.
//               LDS 34816 (Wbt aliased after bfr load) + ~100 VGPR -> 4 blocks/CU, 16 waves/CU.
//               Strides back to 136/168 (R8's 132 made rows 8B-aligned -> split b128 = regression).
//   K3 midgemm: 512 blocks x 512 threads, 8 row-tiles/block -> 16 waves/CU.
//   K4 layer2 : same cooperative structure; pool max kept in registers, one atomicMax/lane at end.
//   K5 cls    : out = g @ Wc + bc
// MFMA layouts per verified m89/m97 mappings.

typedef __bf16 bf16x8 __attribute__((ext_vector_type(8)));
typedef float  f32x4  __attribute__((ext_vector_type(4)));

#define LDSA __attribute__((aligned(16)))

// ---------------------------------------------------------------- K1: KNN
__global__ __launch_bounds__(512) void knn_kernel(const float* __restrict__ pos,
                                                  int* __restrict__ nbr) {
  __shared__ LDSA float4 P4[2048];  // {-2x, -2y, -2z, |q|^2}
  const int blk = blockIdx.x;
  const int b = blk >> 5;
  const int tid = threadIdx.x;
  const size_t bbase = (size_t)b * 2048;
  for (int idx = tid; idx < 2048; idx += 512) {
    const float* pp = pos + (bbase + idx) * 3;
    float x = pp[0], y = pp[1], z = pp[2];
    P4[idx] = make_float4(-2.0f * x, -2.0f * y, -2.0f * z, fmaf(z, z, fmaf(y, y, x * x)));
  }
  __syncthreads();
  const int wave = tid >> 6, lane = tid & 63;
  const int p0 = (blk & 31) * 64 + wave * 8;
  const unsigned long long below = (1ull << lane) - 1ull;
  const float FINF = __uint_as_float(0x7F800000u);
  for (int it = 0; it < 8; ++it) {
    const int pl = p0 + it;
    const float4 Qp = P4[pl];
    const float Px = -0.5f * Qp.x, Py = -0.5f * Qp.y, Pz = -0.5f * Qp.z;
    float m1 = FINF, m2 = FINF, m3 = FINF;
    unsigned s1 = 0, s2 = 0, s3 = 0;
#pragma unroll 8
    for (int i = 0; i < 32; ++i) {
      int c = lane + (i << 6);
      float4 Q = P4[c];
      float d2 = fmaf(Px, Q.x, fmaf(Py, Q.y, fmaf(Pz, Q.z, Q.w)));
      bool c1 = d2 < m1, c2 = d2 < m2, c3 = d2 < m3;
      float n3 = __builtin_amdgcn_fmed3f(d2, m2, m3);
      float n2 = __builtin_amdgcn_fmed3f(d2, m1, m2);
      float n1 = fminf(d2, m1);
      s3 = c2 ? s2 : (c3 ? (unsigned)c : s3);
      s2 = c1 ? s1 : (c2 ? (unsigned)c : s2);
      s1 = c1 ? (unsigned)c : s1;
      m1 = n1; m2 = n2; m3 = n3;
    }
    unsigned u, k1, k2, k3;
    u = __float_as_uint(m1); k1 = ((int)u < 0) ? ~u : (u | 0x80000000u);
    u = __float_as_uint(m2); k2 = ((int)u < 0) ? ~u : (u | 0x80000000u);
    u = __float_as_uint(m3); k3 = ((int)u < 0) ? ~u : (u | 0x80000000u);
    unsigned v = 0;
#pragma unroll
    for (int bit = 31; bit >= 0; --bit) {
      unsigned t = v | (1u << bit);
      int cnt = __popcll(__ballot(k1 < t)) + __popcll(__ballot(k2 < t)) +
                __popcll(__ballot(k3 < t));
      if (cnt < 16) v = t;
    }
    const unsigned V = v;
    const long long outbase = ((long long)bbase + pl) * 16;
    if (__any(k3 < V)) {
      unsigned long long K1 = ((unsigned long long)k1 << 32) | s1;
      unsigned long long K2 = ((unsigned long long)k2 << 32) | s2;
      unsigned long long K3 = ((unsigned long long)k3 << 32) | s3;
      unsigned long long lastk = 0;
      for (int r = 0; r < 16; ++r) {
        unsigned long long k = K1, kmin = K1;
#pragma unroll
        for (int off = 1; off < 64; off <<= 1) {
          unsigned long long o = __shfl_xor(kmin, off);
          kmin = (o < kmin) ? o : kmin;
        }
        if (lane == r) nbr[outbase + r] = (int)(kmin & 0xFFFFFFFFull);
        if (k == kmin) { lastk = k; K1 = K2; K2 = K3; K3 = ~0ull; }
        if (r < 15 && __any(K1 == ~0ull)) {
          if (K1 == ~0ull) {
            unsigned long long best = ~0ull;
            for (int i = 0; i < 32; ++i) {
              int c = lane + (i << 6);
              float4 Q = P4[c];
              float d2 = fmaf(Px, Q.x, fmaf(Py, Q.y, fmaf(Pz, Q.z, Q.w)));
              unsigned uu = __float_as_uint(d2);
              uu = ((int)uu < 0) ? ~uu : (uu | 0x80000000u);
              unsigned long long kc = ((unsigned long long)uu << 32) | (unsigned)c;
              bool ok = (kc > lastk) & (kc < best);
              best = ok ? kc : best;
            }
            K1 = best;
          }
        }
      }
    } else {
      unsigned long long L1 = __ballot(k1 < V), L2 = __ballot(k2 < V), L3 = __ballot(k3 < V);
      unsigned long long E1 = __ballot(k1 == V), E2 = __ballot(k2 == V), E3 = __ballot(k3 == V);
      int cA = __popcll(L1), cB = cA + __popcll(L2), cT = cB + __popcll(L3);
      int eA = __popcll(E1), eB = eA + __popcll(E2);
      {
        bool lt = k1 < V, eq = k1 == V;
        int plt = __popcll(L1 & below);
        int peq = cT + __popcll(E1 & below);
        int p = lt ? plt : peq;
        if (lt || (eq && peq < 16)) nbr[outbase + p] = (int)s1;
      }
      {
        bool lt = k2 < V, eq = k2 == V;
        int plt = cA + __popcll(L2 & below);
        int peq = cT + eA + __popcll(E2 & below);
        int p = lt ? plt : peq;
        if (lt || (eq && peq < 16)) nbr[outbase + p] = (int)s2;
      }
      {
        bool lt = k3 < V, eq = k3 == V;
        int plt = cB + __popcll(L3 & below);
        int peq = cT + eB + __popcll(E3 & below);
        int p = lt ? plt : peq;
        if (lt || (eq && peq < 16)) nbr[outbase + p] = (int)s3;
      }
    }
  }
}

// ---------------------------------------------------------------- K2: layer 1 (block-cooperative)
__global__ __launch_bounds__(256) void layer1_kernel(
    const float* __restrict__ pos, const int* __restrict__ nbr,
    const float* __restrict__ W1a, const float* __restrict__ b1a,
    const float* __restrict__ W1b, const float* __restrict__ b1b,
    __bf16* __restrict__ h1e) {
  __shared__ LDSA char smem[34816];  // Wbt [128][136] bf16; later mt[2][16*136] + base[2][128]
  __bf16* Wbt = (__bf16*)smem;
  const int tid = threadIdx.x;
  for (int idx = tid; idx < 16384; idx += 256) {
    int k = idx >> 7, n = idx & 127;
    Wbt[n * 136 + k] = (__bf16)W1b[idx];
  }
  __syncthreads();
  const int wave = tid >> 6, lane = tid & 63;
  const int q = lane >> 4, c15 = lane & 15;
  bf16x8 bfr[2][4];  // this wave's 2 output tiles (32 VGPR)
#pragma unroll
  for (int i = 0; i < 2; ++i)
#pragma unroll
    for (int t = 0; t < 4; ++t)
      bfr[i][t] = *(const bf16x8*)&Wbt[((2 * wave + i) * 16 + c15) * 136 + t * 32 + q * 8];
  __syncthreads();  // Wbt dead
  __bf16* mt = (__bf16*)smem;           // [2][16*136]  (8704 B)
  float* base = (float*)(smem + 8704);  // [2][128]     (1024 B)
  const int nb = tid >> 4;              // neighbor row this thread builds
  const int ch0 = (tid & 15) * 8;       // channel block this thread builds
  // (A+B) rows for this thread's 8 channels
  float4 S0a, S0b, S1a, S1b, S2a, S2b;
  {
    float4 a, r;
    a = *(const float4*)&W1a[ch0];           r = *(const float4*)&W1a[384 + ch0];
    S0a = make_float4(a.x + r.x, a.y + r.y, a.z + r.z, a.w + r.w);
    a = *(const float4*)&W1a[ch0 + 4];       r = *(const float4*)&W1a[388 + ch0];
    S0b = make_float4(a.x + r.x, a.y + r.y, a.z + r.z, a.w + r.w);
    a = *(const float4*)&W1a[128 + ch0];     r = *(const float4*)&W1a[512 + ch0];
    S1a = make_float4(a.x + r.x, a.y + r.y, a.z + r.z, a.w + r.w);
    a = *(const float4*)&W1a[132 + ch0];     r = *(const float4*)&W1a[516 + ch0];
    S1b = make_float4(a.x + r.x, a.y + r.y, a.z + r.z, a.w + r.w);
    a = *(const float4*)&W1a[256 + ch0];     r = *(const float4*)&W1a[640 + ch0];
    S2a = make_float4(a.x + r.x, a.y + r.y, a.z + r.z, a.w + r.w);
    a = *(const float4*)&W1a[260 + ch0];     r = *(const float4*)&W1a[644 + ch0];
    S2b = make_float4(a.x + r.x, a.y + r.y, a.z + r.z, a.w + r.w);
  }
  const int cb = tid & 127;  // base-producer channel
  const float br0 = W1a[384 + cb], br1 = W1a[512 + cb], br2 = W1a[640 + cb];
  const float ba = b1a[cb];
  const float bia0 = b1b[(2 * wave) * 16 + c15];
  const float bia1 = b1b[(2 * wave + 1) * 16 + c15];
  const int blk = blockIdx.x, b = blk >> 5;
  const size_t bbase = (size_t)b * 2048;
  size_t node = bbase + (blk & 31) * 64;
  // prefetch it=0
  int jc = nbr[node * 16 + nb];
  const float* pj0 = pos + (bbase + jc) * 3;
  float xj = pj0[0], yj = pj0[1], zj = pj0[2];
  float xp = pos[node * 3], yp = pos[node * 3 + 1], zp = pos[node * 3 + 2];
  if (tid < 128) base[cb] = ba - fmaf(xp, br0, fmaf(yp, br1, zp * br2));
  __syncthreads();
  for (int it = 0; it < 64; ++it) {
    const int cur = it & 1, nxt = cur ^ 1;
    float xjn = 0.f, yjn = 0.f, zjn = 0.f, xpn = 0.f, ypn = 0.f, zpn = 0.f;
    if (it < 63) {  // prefetch it+1 + produce base[nxt]
      const size_t node1 = node + 1;
      const int jn = nbr[node1 * 16 + nb];
      xpn = pos[node1 * 3]; ypn = pos[node1 * 3 + 1]; zpn = pos[node1 * 3 + 2];
      const float* pjn = pos + (bbase + jn) * 3;
      xjn = pjn[0]; yjn = pjn[1]; zjn = pjn[2];
      if (tid < 128) base[nxt * 128 + cb] = ba - fmaf(xpn, br0, fmaf(ypn, br1, zpn * br2));
    }
    // build this point's msg row (1 neighbor x 8 channels)
    float4 bb0 = *(const float4*)&base[cur * 128 + ch0];
    float4 bb1 = *(const float4*)&base[cur * 128 + ch0 + 4];
    bf16x8 o;
    o[0] = (__bf16)fmaxf(fmaf(xj, S0a.x, fmaf(yj, S1a.x, fmaf(zj, S2a.x, bb0.x))), 0.f);
    o[1] = (__bf16)fmaxf(fmaf(xj, S0a.y, fmaf(yj, S1a.y, fmaf(zj, S2a.y, bb0.y))), 0.f);
    o[2] = (__bf16)fmaxf(fmaf(xj, S0a.z, fmaf(yj, S1a.z, fmaf(zj, S2a.z, bb0.z))), 0.f);
    o[3] = (__bf16)fmaxf(fmaf(xj, S0a.w, fmaf(yj, S1a.w, fmaf(zj, S2a.w, bb0.w))), 0.f);
    o[4] = (__bf16)fmaxf(fmaf(xj, S0b.x, fmaf(yj, S1b.x, fmaf(zj, S2b.x, bb1.x))), 0.f);
    o[5] = (__bf16)fmaxf(fmaf(xj, S0b.y, fmaf(yj, S1b.y, fmaf(zj, S2b.y, bb1.y))), 0.f);
    o[6] = (__bf16)fmaxf(fmaf(xj, S0b.z, fmaf(yj, S1b.z, fmaf(zj, S2b.z, bb1.z))), 0.f);
    o[7] = (__bf16)fmaxf(fmaf(xj, S0b.w, fmaf(yj, S1b.w, fmaf(zj, S2b.w, bb1.w))), 0.f);
    *(bf16x8*)&mt[cur * 2176 + nb * 136 + ch0] = o;
    __syncthreads();  // the ONE barrier per point: mt[cur]+base[nxt] ready
    bf16x8 af[4];
#pragma unroll
    for (int t = 0; t < 4; ++t)
      af[t] = *(const bf16x8*)&mt[cur * 2176 + c15 * 136 + t * 32 + q * 8];
    f32x4 acc[2] = {};
#pragma unroll
    for (int i = 0; i < 2; ++i)
#pragma unroll
      for (int t = 0; t < 4; ++t)
        acc[i] = __builtin_amdgcn_mfma_f32_16x16x32_bf16(af[t], bfr[i][t], acc[i], 0, 0, 0);
#pragma unroll
    for (int i = 0; i < 2; ++i) {
      float m4 = fmaxf(fmaxf(acc[i][0], acc[i][1]), fmaxf(acc[i][2], acc[i][3]));
      m4 = fmaxf(m4, __shfl_xor(m4, 16));
      m4 = fmaxf(m4, __shfl_xor(m4, 32));
      if (q == i) {
        float bias = i ? bia1 : bia0;
        h1e[node * 160 + (2 * wave + i) * 16 + c15] = (__bf16)fmaxf(m4 + bias, 0.f);
      }
    }
    if (tid < 32) {  // append pos (bf16) + zero pad: cols 128..159
      __bf16 v = (__bf16)0.f;
      if (tid == 0) v = (__bf16)xp;
      else if (tid == 1) v = (__bf16)yp;
      else if (tid == 2) v = (__bf16)zp;
      h1e[node * 160 + 128 + tid] = v;
    }
    node += 1;
    xj = xjn; yj = yjn; zj = zjn; xp = xpn; yp = ypn; zp = zpn;
  }
}

// ---------------------------------------------------------------- K3: u2' = [h1|pos|0] @ W2a + b2a (bf16 out)
__global__ __launch_bounds__(512) void mid_gemm_kernel(
    const __bf16* __restrict__ h1e, const float* __restrict__ W2a,
    const float* __restrict__ b2a, __bf16* __restrict__ u2p) {
  __shared__ LDSA __bf16 Wt[128 * 168];  // W2a^T [n][k], k padded 131->168 (16B-aligned rows)
  const int tid = threadIdx.x;
  uint4 z = make_uint4(0, 0, 0, 0);
  for (int idx = tid; idx < 2688; idx += 512) ((uint4*)Wt)[idx] = z;
  __syncthreads();
  for (int idx = tid; idx < 131 * 32; idx += 512) {
    int k = idx >> 5, c4 = (idx & 31) * 4;
    float4 w = *(const float4*)&W2a[k * 128 + c4];
    Wt[(c4 + 0) * 168 + k] = (__bf16)w.x;
    Wt[(c4 + 1) * 168 + k] = (__bf16)w.y;
    Wt[(c4 + 2) * 168 + k] = (__bf16)w.z;
    Wt[(c4 + 3) * 168 + k] = (__bf16)w.w;
  }
  const int wave = tid >> 6, lane = tid & 63;
  const int q = lane >> 4, c15 = lane & 15;
  float biasr[8];
#pragma unroll
  for (int nt = 0; nt < 8; ++nt) biasr[nt] = b2a[nt * 16 + c15];
  __syncthreads();
  const int row0 = blockIdx.x * 128 + wave * 16;  // 8 waves x 16 rows = 128 rows/block
  bf16x8 af[5];
#pragma unroll
  for (int t = 0; t < 5; ++t)
    af[t] = *(const bf16x8*)(h1e + (size_t)(row0 + c15) * 160 + t * 32 + q * 8);
  f32x4 acc[8] = {};
#pragma unroll
  for (int nt = 0; nt < 8; ++nt)
#pragma unroll
    for (int t = 0; t < 5; ++t) {
      bf16x8 bf = *(const bf16x8*)&Wt[(nt * 16 + c15) * 168 + t * 32 + q * 8];
      acc[nt] = __builtin_amdgcn_mfma_f32_16x16x32_bf16(af[t], bf, acc[nt], 0, 0, 0);
    }
#pragma unroll
  for (int nt = 0; nt < 8; ++nt) {
#pragma unroll
    for (int r = 0; r < 4; ++r)
      u2p[(size_t)(row0 + q * 4 + r) * 128 + nt * 16 + c15] = (__bf16)(acc[nt][r] + biasr[nt]);
  }
}

// ---------------------------------------------------------------- K4: layer 2 + fused pool (block-cooperative)
__global__ __launch_bounds__(256) void layer2_kernel(
    const float* __restrict__ pos, const int* __restrict__ nbr,
    const __bf16* __restrict__ u2p, const float* __restrict__ W2a,
    const float* __restrict__ W2b, const float* __restrict__ b2b,
    int* __restrict__ gG) {
  __shared__ LDSA char smem[34816];  // Wbt; later mt[2][16*136] + proj[2][128]
  __bf16* Wbt = (__bf16*)smem;
  const int tid = threadIdx.x;
  for (int idx = tid; idx < 16384; idx += 256) {
    int k = idx >> 7, n = idx & 127;
    Wbt[n * 136 + k] = (__bf16)W2b[idx];
  }
  __syncthreads();
  const int wave = tid >> 6, lane = tid & 63;
  const int q = lane >> 4, c15 = lane & 15;
  bf16x8 bfr[2][4];
#pragma unroll
  for (int i = 0; i < 2; ++i)
#pragma unroll
    for (int t = 0; t < 4; ++t)
      bfr[i][t] = *(const bf16x8*)&Wbt[((2 * wave + i) * 16 + c15) * 136 + t * 32 + q * 8];
  __syncthreads();  // Wbt dead
  __bf16* mt = (__bf16*)smem;
  float* proj = (float*)(smem + 8704);  // [2][128]
  const int nb = tid >> 4;
  const int ch0 = (tid & 15) * 8;
  const int cb = tid & 127;
  const float r0 = W2a[16384 + cb], r1 = W2a[16512 + cb], r2 = W2a[16640 + cb];
  const float bia0 = b2b[(2 * wave) * 16 + c15];
  const float bia1 = b2b[(2 * wave + 1) * 16 + c15];
  // XCD swizzle: graph g's 32 blocks -> one XCD (perf-only)
  const int lb = blockIdx.x;
  const int xcd = lb & 7, slot = lb >> 3;
  const int b = xcd + 8 * (slot >> 5);
  const int bi = slot & 31;
  const size_t bbase = (size_t)b * 2048;
  size_t node = bbase + bi * 64;
  // prefetch it=0
  int jc = nbr[node * 16 + nb];
  bf16x8 uc = *(const bf16x8*)(u2p + (size_t)(bbase + jc) * 128 + ch0);
  float xp = pos[node * 3], yp = pos[node * 3 + 1], zp = pos[node * 3 + 2];
  if (tid < 128) proj[cb] = fmaf(xp, r0, fmaf(yp, r1, zp * r2));
  __syncthreads();
  float rmax0 = 0.f, rmax1 = 0.f;  // running pool max (relu >= 0)
  for (int it = 0; it < 64; ++it) {
    const int cur = it & 1, nxt = cur ^ 1;
    bf16x8 un = {};
    if (it < 63) {
      const size_t node1 = node + 1;
      const int jn = nbr[node1 * 16 + nb];
      un = *(const bf16x8*)(u2p + (size_t)(bbase + jn) * 128 + ch0);
      const float xpn = pos[node1 * 3], ypn = pos[node1 * 3 + 1], zpn = pos[node1 * 3 + 2];
      if (tid < 128) proj[nxt * 128 + cb] = fmaf(xpn, r0, fmaf(ypn, r1, zpn * r2));
    }
    float4 p0 = *(const float4*)&proj[cur * 128 + ch0];
    float4 p1 = *(const float4*)&proj[cur * 128 + ch0 + 4];
    bf16x8 o;
    o[0] = (__bf16)fmaxf((float)uc[0] - p0.x, 0.f);
    o[1] = (__bf16)fmaxf((float)uc[1] - p0.y, 0.f);
    o[2] = (__bf16)fmaxf((float)uc[2] - p0.z, 0.f);
    o[3] = (__bf16)fmaxf((float)uc[3] - p0.w, 0.f);
    o[4] = (__bf16)fmaxf((float)uc[4] - p1.x, 0.f);
    o[5] = (__bf16)fmaxf((float)uc[5] - p1.y, 0.f);
    o[6] = (__bf16)fmaxf((float)uc[6] - p1.z, 0.f);
    o[7] = (__bf16)fmaxf((float)uc[7] - p1.w, 0.f);
    *(bf16x8*)&mt[cur * 2176 + nb * 136 + ch0] = o;
    __syncthreads();
    bf16x8 af[4];
#pragma unroll
    for (int t = 0; t < 4; ++t)
      af[t] = *(const bf16x8*)&mt[cur * 2176 + c15 * 136 + t * 32 + q * 8];
    f32x4 acc[2] = {};
#pragma unroll
    for (int i = 0; i < 2; ++i)
#pragma unroll
      for (int t = 0; t < 4; ++t)
        acc[i] = __builtin_amdgcn_mfma_f32_16x16x32_bf16(af[t], bfr[i][t], acc[i], 0, 0, 0);
    {
      float m4 = fmaxf(fmaxf(acc[0][0], acc[0][1]), fmaxf(acc[0][2], acc[0][3]));
      m4 = fmaxf(m4, __shfl_xor(m4, 16));
      m4 = fmaxf(m4, __shfl_xor(m4, 32));
      rmax0 = fmaxf(rmax0, fmaxf(m4 + bia0, 0.f));
    }
    {
      float m4 = fmaxf(fmaxf(acc[1][0], acc[1][1]), fmaxf(acc[1][2], acc[1][3]));
      m4 = fmaxf(m4, __shfl_xor(m4, 16));
      m4 = fmaxf(m4, __shfl_xor(m4, 32));
      rmax1 = fmaxf(rmax1, fmaxf(m4 + bia1, 0.f));
    }
    node += 1;
    uc = un;
  }
  if (q == 0) atomicMax(&gG[b * 128 + (2 * wave) * 16 + c15], __float_as_int(rmax0));
  if (q == 1) atomicMax(&gG[b * 128 + (2 * wave + 1) * 16 + c15], __float_as_int(rmax1));
}

// ---------------------------------------------------------------- K5: classifier
__global__ __launch_bounds__(64) void cls_kernel(const int* __restrict__ gG,
                                                 const float* __restrict__ Wc,
                                                 const float* __restrict__ bc,
                                                 float* __restrict__ out) {
  const int b = blockIdx.x, lane = threadIdx.x;
  float g1 = __int_as_float(gG[b * 128 + lane]);
  float g2 = __int_as_float(gG[b * 128 + 64 + lane]);
  float accn[10];
#pragma unroll
  for (int n = 0; n < 10; ++n)
    accn[n] = g1 * Wc[lane * 10 + n] + g2 * Wc[(64 + lane) * 10 + n];
#pragma unroll
  for (int n = 0; n < 10; ++n) {
#pragma unroll
    for (int off = 32; off >= 1; off >>= 1) accn[n] += __shfl_xor(accn[n], off);
  }
  if (lane == 0) {
#pragma unroll
    for (int n = 0; n < 10; ++n) out[b * 10 + n] = accn[n] + bc[n];
  }
}

// ---------------------------------------------------------------- launcher
extern "C" void kernel_launch(void* const* d_in, const int* in_sizes, int n_in,
                              void* d_out, int out_size, void* d_ws, size_t ws_size,
                              hipStream_t stream) {
  const float* pos = (const float*)d_in[0];
  // d_in[1] = batch (unused: graphs are equal-size, sorted)
  const float* W1a = (const float*)d_in[2];
  const float* b1a = (const float*)d_in[3];
  const float* W1b = (const float*)d_in[4];
  const float* b1b = (const float*)d_in[5];
  const float* W2a = (const float*)d_in[6];
  const float* b2a = (const float*)d_in[7];
  const float* W2b = (const float*)d_in[8];
  const float* b2b = (const float*)d_in[9];
  const float* Wc  = (const float*)d_in[10];
  const float* bc  = (const float*)d_in[11];

  char* ws = (char*)d_ws;
  int*    nbr = (int*)ws;                          //  4 MB : [65536][16]
  __bf16* h1e = (__bf16*)(ws + 4194304);           // 20 MB : [65536][160]
  __bf16* u2p = (__bf16*)(ws + 25165824);          // 16 MB : [65536][128] bf16
  int*    gG  = (int*)(ws + 41943040);             // 16 KB : [32][128]
  float*  out = (float*)d_out;

  hipMemsetAsync(gG, 0, 32 * 128 * sizeof(int), stream);  // relu>=0, bits(0)==0.0f
  knn_kernel<<<1024, 512, 0, stream>>>(pos, nbr);
  layer1_kernel<<<1024, 256, 0, stream>>>(pos, nbr, W1a, b1a, W1b, b1b, h1e);
  mid_gemm_kernel<<<512, 512, 0, stream>>>(h1e, W2a, b2a, u2p);
  layer2_kernel<<<1024, 256, 0, stream>>>(pos, nbr, u2p, W2a, W2b, b2b, gG);
  cls_kernel<<<32, 64, 0, stream>>>(gG, Wc, bc, out);
}